// Round 6
// baseline (1641.293 us; speedup 1.0000x reference)
//
#include <hip/hip_runtime.h>

#define HID 128
#define NH 8
#define DH 16
#define NLAYERS 7
#define MLP_IN 285
#define MP 288          // padded MLP dim (18 x 16)
#define LDW 296         // LDS row stride in bf16 elems

typedef short short8 __attribute__((ext_vector_type(8)));
typedef float f32x4 __attribute__((ext_vector_type(4)));
typedef float f32x16 __attribute__((ext_vector_type(16)));
typedef unsigned short ushort8 __attribute__((ext_vector_type(8)));

__device__ inline unsigned short f2bf(float f) {
    union { float f; unsigned int u; } v; v.f = f;
    unsigned int r = v.u + 0x7FFF + ((v.u >> 16) & 1);
    return (unsigned short)(r >> 16);
}
__device__ inline float bf2f(unsigned short u) {
    union { unsigned int u; float f; } v; v.u = ((unsigned int)u) << 16;
    return v.f;
}

// ---------------- embed ----------------
__global__ __launch_bounds__(256) void embed_kernel(
    const float* __restrict__ nf, const float* __restrict__ We,
    const float* __restrict__ be, float* __restrict__ h, int N)
{
    int idx = blockIdx.x * 256 + threadIdx.x;
    if (idx >= N * HID) return;
    int n = idx >> 7, j = idx & 127;
    h[idx] = fmaf(nf[n * 2], We[j], fmaf(nf[n * 2 + 1], We[HID + j], be[j]));
}

// ---------------- fused LN1 + QKV: 32 rows/block ----------------
__global__ __launch_bounds__(256) void ln_qkv_kernel(
    const float* __restrict__ h,
    const float* __restrict__ g, const float* __restrict__ bb,
    const float* __restrict__ WQ, const float* __restrict__ bQ,
    const float* __restrict__ WK, const float* __restrict__ bK,
    const float* __restrict__ WV, const float* __restrict__ bV,
    float* __restrict__ qo, float* __restrict__ ko, float* __restrict__ vo, int M)
{
    __shared__ float Xs[32][132];
    int tid = threadIdx.x;
    int lane = tid & 63, wave = tid >> 6;
    int rowBase = blockIdx.x * 32;

    for (int i = 0; i < 8; ++i) {
        int r = wave * 8 + i;
        int row = rowBase + r;
        float a0 = 0.f, a1 = 0.f;
        if (row < M) {
            a0 = h[(size_t)row * HID + lane];
            a1 = h[(size_t)row * HID + 64 + lane];
        }
        float s = a0 + a1;
#pragma unroll
        for (int off = 32; off > 0; off >>= 1) s += __shfl_down(s, off, 64);
        s = __shfl(s, 0, 64);
        float mu = s * (1.0f / 128.0f);
        float d0 = a0 - mu, d1 = a1 - mu;
        float v = d0 * d0 + d1 * d1;
#pragma unroll
        for (int off = 32; off > 0; off >>= 1) v += __shfl_down(v, off, 64);
        v = __shfl(v, 0, 64);
        float rr = rsqrtf(v * (1.0f / 128.0f) + 1e-5f);
        Xs[r][lane]      = d0 * rr * g[lane] + bb[lane];
        Xs[r][64 + lane] = d1 * rr * g[64 + lane] + bb[64 + lane];
    }
    __syncthreads();

    int cg = tid & 31;
    int rg = tid >> 5;

    const float* Ws[3] = {WQ, WK, WV};
    const float* bs[3] = {bQ, bK, bV};
    float* Os[3] = {qo, ko, vo};

    for (int m = 0; m < 3; ++m) {
        const float* __restrict__ W = Ws[m];
        float acc[4][4];
#pragma unroll
        for (int i = 0; i < 4; ++i)
#pragma unroll
            for (int j = 0; j < 4; ++j) acc[i][j] = 0.f;
        for (int k = 0; k < 128; k += 4) {
            float4 a[4];
#pragma unroll
            for (int i = 0; i < 4; ++i) a[i] = *(const float4*)&Xs[rg * 4 + i][k];
#pragma unroll
            for (int kk = 0; kk < 4; ++kk) {
                float4 w = *(const float4*)&W[(size_t)(k + kk) * HID + cg * 4];
#pragma unroll
                for (int i = 0; i < 4; ++i) {
                    float av = ((const float*)&a[i])[kk];
                    acc[i][0] = fmaf(av, w.x, acc[i][0]);
                    acc[i][1] = fmaf(av, w.y, acc[i][1]);
                    acc[i][2] = fmaf(av, w.z, acc[i][2]);
                    acc[i][3] = fmaf(av, w.w, acc[i][3]);
                }
            }
        }
        float4 bv = *(const float4*)&bs[m][cg * 4];
#pragma unroll
        for (int i = 0; i < 4; ++i) {
            int row = rowBase + rg * 4 + i;
            if (row < M) {
                float4 c;
                c.x = acc[i][0] + bv.x; c.y = acc[i][1] + bv.y;
                c.z = acc[i][2] + bv.z; c.w = acc[i][3] + bv.w;
                *(float4*)&Os[m][(size_t)row * HID + cg * 4] = c;
            }
        }
    }
}

// ---------------- fused WO+res -> LN2 -> W1+relu -> W2+res ----------------
__global__ __launch_bounds__(256) void post_kernel(
    const float* __restrict__ at, const float* __restrict__ hin,
    const float* __restrict__ WO, const float* __restrict__ bO,
    const float* __restrict__ g2, const float* __restrict__ b2g,
    const float* __restrict__ W1, const float* __restrict__ b1,
    const float* __restrict__ W2, const float* __restrict__ b2,
    float* __restrict__ hout, int M)
{
    __shared__ float As[32][132];
    __shared__ float Hs[32][132];
    __shared__ float Ts[32][132];
    int tid = threadIdx.x;
    int lane = tid & 63, wave = tid >> 6;
    int rowBase = blockIdx.x * 32;
    int cg = tid & 31;
    int rg = tid >> 5;

    for (int i = tid; i < 32 * 32; i += 256) {
        int r = i >> 5, c4 = i & 31;
        int row = rowBase + r;
        float4 va = make_float4(0.f, 0.f, 0.f, 0.f), vh = va;
        if (row < M) {
            va = *(const float4*)&at[(size_t)row * HID + c4 * 4];
            vh = *(const float4*)&hin[(size_t)row * HID + c4 * 4];
        }
        *(float4*)&As[r][c4 * 4] = va;
        *(float4*)&Hs[r][c4 * 4] = vh;
    }
    __syncthreads();

    {
        float acc[4][4];
#pragma unroll
        for (int i = 0; i < 4; ++i)
#pragma unroll
            for (int j = 0; j < 4; ++j) acc[i][j] = 0.f;
        for (int k = 0; k < 128; k += 4) {
            float4 a[4];
#pragma unroll
            for (int i = 0; i < 4; ++i) a[i] = *(const float4*)&As[rg * 4 + i][k];
#pragma unroll
            for (int kk = 0; kk < 4; ++kk) {
                float4 w = *(const float4*)&WO[(size_t)(k + kk) * HID + cg * 4];
#pragma unroll
                for (int i = 0; i < 4; ++i) {
                    float av = ((const float*)&a[i])[kk];
                    acc[i][0] = fmaf(av, w.x, acc[i][0]);
                    acc[i][1] = fmaf(av, w.y, acc[i][1]);
                    acc[i][2] = fmaf(av, w.z, acc[i][2]);
                    acc[i][3] = fmaf(av, w.w, acc[i][3]);
                }
            }
        }
        float4 bv = *(const float4*)&bO[cg * 4];
#pragma unroll
        for (int i = 0; i < 4; ++i) {
            float* hp = &Hs[rg * 4 + i][cg * 4];
            hp[0] += acc[i][0] + bv.x;
            hp[1] += acc[i][1] + bv.y;
            hp[2] += acc[i][2] + bv.z;
            hp[3] += acc[i][3] + bv.w;
        }
    }
    __syncthreads();

    for (int i = 0; i < 8; ++i) {
        int r = wave * 8 + i;
        float a0 = Hs[r][lane];
        float a1 = Hs[r][64 + lane];
        float s = a0 + a1;
#pragma unroll
        for (int off = 32; off > 0; off >>= 1) s += __shfl_down(s, off, 64);
        s = __shfl(s, 0, 64);
        float mu = s * (1.0f / 128.0f);
        float d0 = a0 - mu, d1 = a1 - mu;
        float v = d0 * d0 + d1 * d1;
#pragma unroll
        for (int off = 32; off > 0; off >>= 1) v += __shfl_down(v, off, 64);
        v = __shfl(v, 0, 64);
        float rr = rsqrtf(v * (1.0f / 128.0f) + 1e-5f);
        As[r][lane]      = d0 * rr * g2[lane] + b2g[lane];
        As[r][64 + lane] = d1 * rr * g2[64 + lane] + b2g[64 + lane];
    }
    __syncthreads();

    {
        float acc[4][4];
#pragma unroll
        for (int i = 0; i < 4; ++i)
#pragma unroll
            for (int j = 0; j < 4; ++j) acc[i][j] = 0.f;
        for (int k = 0; k < 128; k += 4) {
            float4 a[4];
#pragma unroll
            for (int i = 0; i < 4; ++i) a[i] = *(const float4*)&As[rg * 4 + i][k];
#pragma unroll
            for (int kk = 0; kk < 4; ++kk) {
                float4 w = *(const float4*)&W1[(size_t)(k + kk) * HID + cg * 4];
#pragma unroll
                for (int i = 0; i < 4; ++i) {
                    float av = ((const float*)&a[i])[kk];
                    acc[i][0] = fmaf(av, w.x, acc[i][0]);
                    acc[i][1] = fmaf(av, w.y, acc[i][1]);
                    acc[i][2] = fmaf(av, w.z, acc[i][2]);
                    acc[i][3] = fmaf(av, w.w, acc[i][3]);
                }
            }
        }
        float4 bv = *(const float4*)&b1[cg * 4];
#pragma unroll
        for (int i = 0; i < 4; ++i) {
            float* tp = &Ts[rg * 4 + i][cg * 4];
            tp[0] = fmaxf(acc[i][0] + bv.x, 0.f);
            tp[1] = fmaxf(acc[i][1] + bv.y, 0.f);
            tp[2] = fmaxf(acc[i][2] + bv.z, 0.f);
            tp[3] = fmaxf(acc[i][3] + bv.w, 0.f);
        }
    }
    __syncthreads();

    {
        float acc[4][4];
#pragma unroll
        for (int i = 0; i < 4; ++i)
#pragma unroll
            for (int j = 0; j < 4; ++j) acc[i][j] = 0.f;
        for (int k = 0; k < 128; k += 4) {
            float4 a[4];
#pragma unroll
            for (int i = 0; i < 4; ++i) a[i] = *(const float4*)&Ts[rg * 4 + i][k];
#pragma unroll
            for (int kk = 0; kk < 4; ++kk) {
                float4 w = *(const float4*)&W2[(size_t)(k + kk) * HID + cg * 4];
#pragma unroll
                for (int i = 0; i < 4; ++i) {
                    float av = ((const float*)&a[i])[kk];
                    acc[i][0] = fmaf(av, w.x, acc[i][0]);
                    acc[i][1] = fmaf(av, w.y, acc[i][1]);
                    acc[i][2] = fmaf(av, w.z, acc[i][2]);
                    acc[i][3] = fmaf(av, w.w, acc[i][3]);
                }
            }
        }
        float4 bv = *(const float4*)&b2[cg * 4];
#pragma unroll
        for (int i = 0; i < 4; ++i) {
            int row = rowBase + rg * 4 + i;
            if (row < M) {
                float* hp = &Hs[rg * 4 + i][cg * 4];
                float4 c;
                c.x = hp[0] + acc[i][0] + bv.x;
                c.y = hp[1] + acc[i][1] + bv.y;
                c.z = hp[2] + acc[i][2] + bv.z;
                c.w = hp[3] + acc[i][3] + bv.w;
                *(float4*)&hout[(size_t)row * HID + cg * 4] = c;
            }
        }
    }
}

// ---------------- CSR build ----------------
__global__ __launch_bounds__(256) void deg_kernel(
    const int* __restrict__ dst, int* __restrict__ deg, int E)
{
    int e = blockIdx.x * 256 + threadIdx.x;
    if (e < E) atomicAdd(&deg[dst[e]], 1);
}

__global__ __launch_bounds__(256) void scan_kernel(
    const int* __restrict__ deg, int* __restrict__ rowptr,
    int* __restrict__ cursor, int N)
{
    __shared__ int sums[256];
    int tid = threadIdx.x;
    int chunk = (N + 255) / 256;
    int lo = tid * chunk;
    int hi = lo + chunk; if (hi > N) hi = N;
    int s = 0;
    for (int i = lo; i < hi && i >= 0; ++i) s += deg[i];
    sums[tid] = s;
    __syncthreads();
    for (int off = 1; off < 256; off <<= 1) {
        int v = (tid >= off) ? sums[tid - off] : 0;
        __syncthreads();
        sums[tid] += v;
        __syncthreads();
    }
    int base = (tid == 0) ? 0 : sums[tid - 1];
    for (int i = lo; i < hi; ++i) {
        rowptr[i] = base; cursor[i] = base; base += deg[i];
    }
    if (tid == 255) rowptr[N] = sums[255];
}

__global__ __launch_bounds__(256) void scatter_kernel(
    const int* __restrict__ src, const int* __restrict__ dst,
    int* __restrict__ cursor, int* __restrict__ ssrc, int E)
{
    int e = blockIdx.x * 256 + threadIdx.x;
    if (e < E) {
        int p = atomicAdd(&cursor[dst[e]], 1);
        ssrc[p] = src[e];
    }
}

// ---------------- fused segment-softmax attention ----------------
__global__ __launch_bounds__(256) void attn_fused_kernel(
    const float* __restrict__ q, const float* __restrict__ k,
    const float* __restrict__ v, const int* __restrict__ rowptr,
    const int* __restrict__ ssrc, float* __restrict__ at, int N)
{
    int node = blockIdx.x * 4 + (threadIdx.x >> 6);
    int lane = threadIdx.x & 63;
    if (node >= N) return;
    int beg = rowptr[node], end = rowptr[node + 1];
    float q0 = q[(size_t)node * HID + lane];
    float q1 = q[(size_t)node * HID + 64 + lane];
    float acc0 = 0.f, acc1 = 0.f, den0 = 0.f, den1 = 0.f;
    for (int i = beg; i < end; ++i) {
        int s = ssrc[i];
        float k0 = k[(size_t)s * HID + lane];
        float k1 = k[(size_t)s * HID + 64 + lane];
        float p0 = q0 * k0, p1 = q1 * k1;
#pragma unroll
        for (int off = 1; off < 16; off <<= 1) {
            p0 += __shfl_xor(p0, off, 64);
            p1 += __shfl_xor(p1, off, 64);
        }
        float w0 = __expf(p0 * 0.25f);
        float w1 = __expf(p1 * 0.25f);
        den0 += w0; den1 += w1;
        acc0 = fmaf(w0, v[(size_t)s * HID + lane], acc0);
        acc1 = fmaf(w1, v[(size_t)s * HID + 64 + lane], acc1);
    }
    at[(size_t)node * HID + lane]      = (den0 > 0.f) ? acc0 / den0 : 0.f;
    at[(size_t)node * HID + 64 + lane] = (den1 > 0.f) ? acc1 / den1 : 0.f;
}

// ---------------- prep: fragment-major packed bf16 MLP hidden weights ----------------
__global__ __launch_bounds__(256) void prep_wp_kernel(
    const float* __restrict__ Wh, unsigned short* __restrict__ wp)
{
    int idx = blockIdx.x * 256 + threadIdx.x;
    if (idx >= 3 * 9 * 18 * 64) return;
    int lane = idx & 63;
    int r = idx >> 6;
    int kt = r % 18; r /= 18;
    int ct = r % 9;
    int layer = r / 9;
    int n = ct * 32 + (lane & 31);
    int kbase = kt * 16 + (lane >> 5) * 8;
    ushort8 val;
#pragma unroll
    for (int j = 0; j < 8; ++j) {
        int k = kbase + j;
        float v = (n < MLP_IN && k < MLP_IN)
            ? Wh[(size_t)layer * MLP_IN * MLP_IN + (size_t)k * MLP_IN + n] : 0.f;
        val[j] = f2bf(v);
    }
    *(ushort8*)&wp[(size_t)idx * 8] = val;
}

__global__ __launch_bounds__(256) void prep_hb_kernel(
    const float* __restrict__ h, unsigned short* __restrict__ hb, int n)
{
    int idx = blockIdx.x * 256 + threadIdx.x;
    if (idx >= n) return;
    hb[idx] = f2bf(h[idx]);
}

// ---------------- fused edge classifier MLP v3 ----------------
// 192 edges/block, 3 waves x 64 rows, B ct-tiles (18 KB) double-buffered in LDS
// via global_load_lds, prefetched one ct ahead; barrier-pipelined.
__global__ __launch_bounds__(192, 1) void edge_mlp_mfma(
    const unsigned short* __restrict__ hb, const float* __restrict__ ce,
    const float* __restrict__ pe, const float* __restrict__ num,
    const int* __restrict__ src, const int* __restrict__ dst,
    const int* __restrict__ pc, const int* __restrict__ rc,
    const int* __restrict__ pf,
    const unsigned short* __restrict__ wp, const float* __restrict__ bh,
    const float* __restrict__ Wo, const float* __restrict__ bo,
    float* __restrict__ out, int E)
{
    __shared__ unsigned short y[192 * LDW];        // 113664 B
    __shared__ unsigned short bbuf[2][18 * 512];   // 2 x 18432 B
    int tid = threadIdx.x;
    int e0 = blockIdx.x * 192;

    // ---- stage y0: 192 edges x 288 cols bf16; cols 285..287 zero ----
    for (int i = tid; i < 192 * 36; i += 192) {
        int t = i / 36;
        int c = i - t * 36;
        int e = e0 + t;
        if (e >= E) e = E - 1;
        ushort8 val;
        if (c < 16) {
            val = *(const ushort8*)&hb[(size_t)src[e] * HID + c * 8];
        } else if (c < 32) {
            val = *(const ushort8*)&hb[(size_t)dst[e] * HID + (c - 16) * 8];
        } else if (c == 32) {
            const float* p = &ce[pc[e] * 8];
#pragma unroll
            for (int j = 0; j < 8; ++j) val[j] = f2bf(p[j]);
        } else if (c == 33) {
            const float* p = &ce[rc[e] * 8];
#pragma unroll
            for (int j = 0; j < 8; ++j) val[j] = f2bf(p[j]);
        } else if (c == 34) {
            const float* p = &pe[pf[e] * 8];
#pragma unroll
            for (int j = 0; j < 8; ++j) val[j] = f2bf(p[j]);
        } else {
            const float* p = &num[(size_t)e * 5];
#pragma unroll
            for (int j = 0; j < 5; ++j) val[j] = f2bf(p[j]);
            val[5] = 0; val[6] = 0; val[7] = 0;
        }
        *(ushort8*)&y[t * LDW + c * 8] = val;
    }
    __syncthreads();

    int wave = tid >> 6;
    int lane = tid & 63;
    int l31 = lane & 31;
    int half = lane >> 5;

    for (int layer = 0; layer < 3; ++layer) {
        const unsigned short* __restrict__ Wl = wp + (size_t)layer * 9 * 18 * 64 * 8;
        const float* __restrict__ bias = bh + layer * MLP_IN;

        // prefetch ct=0 B tile into bbuf[0] (18*64=1152 chunks of 16B, 192 threads)
#pragma unroll
        for (int i = 0; i < 6; ++i) {
            int idx = i * 192 + tid;
            __builtin_amdgcn_global_load_lds(
                (const __attribute__((address_space(1))) unsigned int*)(Wl + (size_t)idx * 8),
                (__attribute__((address_space(3))) unsigned int*)(&bbuf[0][(size_t)idx * 8]),
                16, 0, 0);
        }

        // A fragments: 2 row-tiles x 18 k-tiles (64 rows per wave)
        short8 afr[2][18];
#pragma unroll
        for (int rt = 0; rt < 2; ++rt)
#pragma unroll
            for (int kt = 0; kt < 18; ++kt)
                afr[rt][kt] = *(const short8*)&y[(wave * 64 + rt * 32 + l31) * LDW + kt * 16 + half * 8];
        __syncthreads();   // prefetch done + all A captured; y writable, bbuf[0] readable

        for (int ct = 0; ct < 9; ++ct) {
            if (ct < 8) {
                const unsigned short* Wn = Wl + (size_t)(ct + 1) * 9216;
                unsigned short* bd = &bbuf[(ct + 1) & 1][0];
#pragma unroll
                for (int i = 0; i < 6; ++i) {
                    int idx = i * 192 + tid;
                    __builtin_amdgcn_global_load_lds(
                        (const __attribute__((address_space(1))) unsigned int*)(Wn + (size_t)idx * 8),
                        (__attribute__((address_space(3))) unsigned int*)(bd + (size_t)idx * 8),
                        16, 0, 0);
                }
            }
            const unsigned short* bp = &bbuf[ct & 1][0];
            f32x16 accE0 = {}, accO0 = {}, accE1 = {}, accO1 = {};
#pragma unroll
            for (int kt = 0; kt < 18; kt += 2) {
                short8 b0 = *(const short8*)&bp[(kt * 64 + lane) * 8];
                short8 b1 = *(const short8*)&bp[((kt + 1) * 64 + lane) * 8];
                accE0 = __builtin_amdgcn_mfma_f32_32x32x16_bf16(afr[0][kt],     b0, accE0, 0, 0, 0);
                accO0 = __builtin_amdgcn_mfma_f32_32x32x16_bf16(afr[0][kt + 1], b1, accO0, 0, 0, 0);
                accE1 = __builtin_amdgcn_mfma_f32_32x32x16_bf16(afr[1][kt],     b0, accE1, 0, 0, 0);
                accO1 = __builtin_amdgcn_mfma_f32_32x32x16_bf16(afr[1][kt + 1], b1, accO1, 0, 0, 0);
            }
            int col = ct * 32 + l31;
            if (col < MLP_IN) {
                float bv = bias[col];
#pragma unroll
                for (int r = 0; r < 16; ++r) {
                    int rowm = (r & 3) + 8 * (r >> 2) + 4 * half;
                    y[(wave * 64 + rowm) * LDW + col]      = f2bf(fmaxf(accE0[r] + accO0[r] + bv, 0.f));
                    y[(wave * 64 + 32 + rowm) * LDW + col] = f2bf(fmaxf(accE1[r] + accO1[r] + bv, 0.f));
                }
            }
            __syncthreads();   // publish next B buffer; lockstep; y writes visible at loop end
        }
    }

    // ---- output layer: [285] @ Wo[285,2] + bo ----
    for (int i = tid; i < 192 * 2; i += 192) {
        int t = i >> 1, oc = i & 1;
        int e = e0 + t;
        if (e < E) {
            const unsigned short* yr = &y[t * LDW];
            float p0 = 0.f, p1 = 0.f, p2 = 0.f, p3 = 0.f;
            for (int kc = 0; kc < 35; ++kc) {
                ushort8 yv = *(const ushort8*)&yr[kc * 8];
                int kb = kc * 8;
                p0 = fmaf(bf2f(yv[0]), Wo[(kb + 0) * 2 + oc], p0);
                p1 = fmaf(bf2f(yv[1]), Wo[(kb + 1) * 2 + oc], p1);
                p2 = fmaf(bf2f(yv[2]), Wo[(kb + 2) * 2 + oc], p2);
                p3 = fmaf(bf2f(yv[3]), Wo[(kb + 3) * 2 + oc], p3);
                p0 = fmaf(bf2f(yv[4]), Wo[(kb + 4) * 2 + oc], p0);
                p1 = fmaf(bf2f(yv[5]), Wo[(kb + 5) * 2 + oc], p1);
                p2 = fmaf(bf2f(yv[6]), Wo[(kb + 6) * 2 + oc], p2);
                p3 = fmaf(bf2f(yv[7]), Wo[(kb + 7) * 2 + oc], p3);
            }
            float acc = bo[oc] + (p0 + p1) + (p2 + p3);
            for (int k = 280; k < MLP_IN; ++k)
                acc = fmaf(bf2f(yr[k]), Wo[k * 2 + oc], acc);
            out[(size_t)e * 2 + oc] = acc;
        }
    }
}

extern "C" void kernel_launch(void* const* d_in, const int* in_sizes, int n_in,
                              void* d_out, int out_size, void* d_ws, size_t ws_size,
                              hipStream_t stream)
{
    const float* node_feats = (const float*)d_in[0];
    const float* numericals = (const float*)d_in[1];
    const float* W_emb = (const float*)d_in[2];
    const float* b_emb = (const float*)d_in[3];
    const float* WQ = (const float*)d_in[4];
    const float* bQ = (const float*)d_in[5];
    const float* WK = (const float*)d_in[6];
    const float* bK = (const float*)d_in[7];
    const float* WV = (const float*)d_in[8];
    const float* bV = (const float*)d_in[9];
    const float* WO = (const float*)d_in[10];
    const float* bO = (const float*)d_in[11];
    const float* ln1_g = (const float*)d_in[12];
    const float* ln1_b = (const float*)d_in[13];
    const float* ln2_g = (const float*)d_in[14];
    const float* ln2_b = (const float*)d_in[15];
    const float* W1 = (const float*)d_in[16];
    const float* b1 = (const float*)d_in[17];
    const float* W2 = (const float*)d_in[18];
    const float* b2 = (const float*)d_in[19];
    const float* curr_emb = (const float*)d_in[20];
    const float* pay_emb = (const float*)d_in[21];
    const float* mlp_Wh = (const float*)d_in[22];
    const float* mlp_bh = (const float*)d_in[23];
    const float* mlp_Wo = (const float*)d_in[24];
    const float* mlp_bo = (const float*)d_in[25];
    const int* src = (const int*)d_in[26];
    const int* dst = (const int*)d_in[27];
    const int* pc = (const int*)d_in[28];
    const int* rc = (const int*)d_in[29];
    const int* pf = (const int*)d_in[30];

    const int N = in_sizes[0] / 2;
    const int E = in_sizes[26];

    float* ws = (float*)d_ws;
    float* h   = ws;
    float* x   = h  + (size_t)N * HID;   // unused slot kept for layout stability
    float* qb  = x  + (size_t)N * HID;
    float* kb  = qb + (size_t)N * HID;
    float* vb  = kb + (size_t)N * HID;
    float* at  = vb + (size_t)N * HID;
    unsigned short* hb = (unsigned short*)(at + (size_t)N * HID);
    unsigned short* wpk = hb + (size_t)N * HID;
    int* rowptr = (int*)(wpk + (size_t)3 * 9 * 18 * 64 * 8);
    int* deg    = rowptr + (N + 1);
    int* cursor = deg + N;
    int* ssrc   = cursor + N;

    prep_wp_kernel<<<(3 * 9 * 18 * 64 + 255) / 256, 256, 0, stream>>>(mlp_Wh, wpk);

    embed_kernel<<<(N * HID + 255) / 256, 256, 0, stream>>>(node_feats, W_emb, b_emb, h, N);

    hipMemsetAsync(deg, 0, (size_t)N * sizeof(int), stream);
    deg_kernel<<<(E + 255) / 256, 256, 0, stream>>>(dst, deg, E);
    scan_kernel<<<1, 256, 0, stream>>>(deg, rowptr, cursor, N);
    scatter_kernel<<<(E + 255) / 256, 256, 0, stream>>>(src, dst, cursor, ssrc, E);

    int nodeBlocks = (N + 31) / 32;

    for (int l = 0; l < NLAYERS; ++l) {
        ln_qkv_kernel<<<nodeBlocks, 256, 0, stream>>>(
            h, ln1_g + l * HID, ln1_b + l * HID,
            WQ + (size_t)l * HID * HID, bQ + l * HID,
            WK + (size_t)l * HID * HID, bK + l * HID,
            WV + (size_t)l * HID * HID, bV + l * HID,
            qb, kb, vb, N);

        attn_fused_kernel<<<(N + 3) / 4, 256, 0, stream>>>(qb, kb, vb, rowptr, ssrc, at, N);

        post_kernel<<<nodeBlocks, 256, 0, stream>>>(
            at, h,
            WO + (size_t)l * HID * HID, bO + l * HID,
            ln2_g + l * HID, ln2_b + l * HID,
            W1 + (size_t)l * HID * HID, b1 + l * HID,
            W2 + (size_t)l * HID * HID, b2 + l * HID,
            h, N);
    }

    prep_hb_kernel<<<(N * HID + 255) / 256, 256, 0, stream>>>(h, hb, N * HID);

    edge_mlp_mfma<<<(E + 191) / 192, 192, 0, stream>>>(
        hb, curr_emb, pay_emb, numericals, src, dst, pc, rc, pf,
        wpk, mlp_bh, mlp_Wo, mlp_bo, (float*)d_out, E);
}

// Round 7
// 1168.900 us; speedup vs baseline: 1.4041x; 1.4041x over previous
//
#include <hip/hip_runtime.h>

#define HID 128
#define NH 8
#define DH 16
#define NLAYERS 7
#define MLP_IN 285
#define MP 288          // padded MLP dim (18 x 16)
#define LDW 296         // LDS row stride in bf16 elems (edge kernel)
#define XS 136          // LDS row stride for node bf16 tiles (16B-aligned rows)

typedef short short8 __attribute__((ext_vector_type(8)));
typedef float f32x4 __attribute__((ext_vector_type(4)));
typedef float f32x16 __attribute__((ext_vector_type(16)));
typedef unsigned short ushort8 __attribute__((ext_vector_type(8)));

__device__ inline unsigned short f2bf(float f) {
    union { float f; unsigned int u; } v; v.f = f;
    unsigned int r = v.u + 0x7FFF + ((v.u >> 16) & 1);
    return (unsigned short)(r >> 16);
}
__device__ inline float bf2f(unsigned short u) {
    union { unsigned int u; float f; } v; v.u = ((unsigned int)u) << 16;
    return v.f;
}

// ---------------- embed ----------------
__global__ __launch_bounds__(256) void embed_kernel(
    const float* __restrict__ nf, const float* __restrict__ We,
    const float* __restrict__ be, float* __restrict__ h, int N)
{
    int idx = blockIdx.x * 256 + threadIdx.x;
    if (idx >= N * HID) return;
    int n = idx >> 7, j = idx & 127;
    h[idx] = fmaf(nf[n * 2], We[j], fmaf(nf[n * 2 + 1], We[HID + j], be[j]));
}

// ---------------- prep: node weights -> fragment-major bf16 hi/lo ----------------
// 42 matrices (7 layers x {WQ,WK,WV,WO,W1,W2}), each 128x128.
// chunk idx = ((m*32 + ct*8 + kt)*64 + lane); elem j: n=ct*32+(lane&31), k=kt*16+(lane>>5)*8+j
__global__ __launch_bounds__(256) void prep_nodew_kernel(
    const float* __restrict__ WQ, const float* __restrict__ WK,
    const float* __restrict__ WV, const float* __restrict__ WO,
    const float* __restrict__ W1, const float* __restrict__ W2,
    unsigned short* __restrict__ wnh, unsigned short* __restrict__ wnl)
{
    int idx = blockIdx.x * 256 + threadIdx.x;
    if (idx >= 42 * 32 * 64) return;
    int lane = idx & 63;
    int r = idx >> 6;
    int kt = r & 7; r >>= 3;
    int ct = r & 3; r >>= 2;
    int m = r;                 // 0..41
    int l = m / 6, wi = m - l * 6;
    const float* Wb;
    switch (wi) {
        case 0: Wb = WQ; break; case 1: Wb = WK; break; case 2: Wb = WV; break;
        case 3: Wb = WO; break; case 4: Wb = W1; break; default: Wb = W2; break;
    }
    Wb += (size_t)l * HID * HID;
    int n = ct * 32 + (lane & 31);
    int kb = kt * 16 + (lane >> 5) * 8;
    ushort8 vh, vl;
#pragma unroll
    for (int j = 0; j < 8; ++j) {
        float w = Wb[(size_t)(kb + j) * HID + n];
        unsigned short hi = f2bf(w);
        vh[j] = hi;
        vl[j] = f2bf(w - bf2f(hi));
    }
    *(ushort8*)&wnh[(size_t)idx * 8] = vh;
    *(ushort8*)&wnl[(size_t)idx * 8] = vl;
}

// ---------------- fused LN1 + QKV via compensated bf16 MFMA: 32 rows/block ----------------
__global__ __launch_bounds__(256, 2) void ln_qkv_mfma(
    const float* __restrict__ h,
    const float* __restrict__ g, const float* __restrict__ bb,
    const unsigned short* __restrict__ wnh, const unsigned short* __restrict__ wnl,
    int matbase,
    const float* __restrict__ bQ, const float* __restrict__ bK, const float* __restrict__ bV,
    float* __restrict__ qo, float* __restrict__ ko, float* __restrict__ vo, int M)
{
    __shared__ unsigned short Xh[32][XS];
    __shared__ unsigned short Xl[32][XS];
    int tid = threadIdx.x;
    int lane = tid & 63, wave = tid >> 6;
    int rowBase = blockIdx.x * 32;

    // LN: 8 rows per wave
    for (int i = 0; i < 8; ++i) {
        int r = wave * 8 + i;
        int row = rowBase + r;
        float a0 = 0.f, a1 = 0.f;
        if (row < M) {
            a0 = h[(size_t)row * HID + lane];
            a1 = h[(size_t)row * HID + 64 + lane];
        }
        float s = a0 + a1;
#pragma unroll
        for (int off = 32; off > 0; off >>= 1) s += __shfl_down(s, off, 64);
        s = __shfl(s, 0, 64);
        float mu = s * (1.0f / 128.0f);
        float d0 = a0 - mu, d1 = a1 - mu;
        float v = d0 * d0 + d1 * d1;
#pragma unroll
        for (int off = 32; off > 0; off >>= 1) v += __shfl_down(v, off, 64);
        v = __shfl(v, 0, 64);
        float rr = rsqrtf(v * (1.0f / 128.0f) + 1e-5f);
        float x0 = d0 * rr * g[lane] + bb[lane];
        float x1 = d1 * rr * g[64 + lane] + bb[64 + lane];
        unsigned short h0 = f2bf(x0), h1 = f2bf(x1);
        Xh[r][lane] = h0;           Xh[r][64 + lane] = h1;
        Xl[r][lane] = f2bf(x0 - bf2f(h0));
        Xl[r][64 + lane] = f2bf(x1 - bf2f(h1));
    }
    __syncthreads();

    int l31 = lane & 31;
    int half = lane >> 5;

    short8 ah[8], al[8];
#pragma unroll
    for (int kt = 0; kt < 8; ++kt) {
        ah[kt] = *(const short8*)&Xh[l31][kt * 16 + half * 8];
        al[kt] = *(const short8*)&Xl[l31][kt * 16 + half * 8];
    }

    const float* bias[3] = {bQ, bK, bV};
    float* outp[3] = {qo, ko, vo};

    for (int m = 0; m < 3; ++m) {
        size_t fb = (((size_t)(matbase + m) * 32 + (size_t)wave * 8) * 64 + lane) * 8;
        const unsigned short* Bh = wnh + fb;
        const unsigned short* Bl = wnl + fb;
        short8 bh[8], bl[8];
#pragma unroll
        for (int kt = 0; kt < 8; ++kt) {
            bh[kt] = *(const short8*)&Bh[kt * 512];
            bl[kt] = *(const short8*)&Bl[kt * 512];
        }
        __builtin_amdgcn_sched_barrier(0);
        f32x16 accA = {}, accB = {};
#pragma unroll
        for (int kt = 0; kt < 8; kt += 2) {
            accA = __builtin_amdgcn_mfma_f32_32x32x16_bf16(ah[kt],     bh[kt],     accA, 0, 0, 0);
            accB = __builtin_amdgcn_mfma_f32_32x32x16_bf16(ah[kt + 1], bh[kt + 1], accB, 0, 0, 0);
        }
#pragma unroll
        for (int kt = 0; kt < 8; kt += 2) {
            accA = __builtin_amdgcn_mfma_f32_32x32x16_bf16(al[kt],     bh[kt],     accA, 0, 0, 0);
            accB = __builtin_amdgcn_mfma_f32_32x32x16_bf16(al[kt + 1], bh[kt + 1], accB, 0, 0, 0);
        }
#pragma unroll
        for (int kt = 0; kt < 8; kt += 2) {
            accA = __builtin_amdgcn_mfma_f32_32x32x16_bf16(ah[kt],     bl[kt],     accA, 0, 0, 0);
            accB = __builtin_amdgcn_mfma_f32_32x32x16_bf16(ah[kt + 1], bl[kt + 1], accB, 0, 0, 0);
        }
        int col = wave * 32 + l31;
        float bv = bias[m][col];
        float* op = outp[m];
#pragma unroll
        for (int r = 0; r < 16; ++r) {
            int rowm = (r & 3) + 8 * (r >> 2) + 4 * half;
            int row = rowBase + rowm;
            if (row < M) op[(size_t)row * HID + col] = accA[r] + accB[r] + bv;
        }
    }
}

// ---------------- fused WO+res -> LN2 -> W1+relu -> W2+res via MFMA: 32 rows/block ----------------
__global__ __launch_bounds__(256, 2) void post_mfma(
    const float* __restrict__ at, const float* __restrict__ hin,
    const unsigned short* __restrict__ wnh, const unsigned short* __restrict__ wnl,
    int matbase,
    const float* __restrict__ bO,
    const float* __restrict__ g2, const float* __restrict__ b2g,
    const float* __restrict__ b1, const float* __restrict__ b2,
    float* __restrict__ hout, int M)
{
    __shared__ unsigned short Ah[32][XS];
    __shared__ unsigned short Al[32][XS];
    __shared__ unsigned short Th[32][XS];
    __shared__ unsigned short Tl[32][XS];
    __shared__ float Hs[32][132];
    int tid = threadIdx.x;
    int lane = tid & 63, wave = tid >> 6;
    int rowBase = blockIdx.x * 32;
    int l31 = lane & 31;
    int half = lane >> 5;

    // stage at (bf16 hi/lo) and h (fp32)
    for (int i = tid; i < 32 * 32; i += 256) {
        int r = i >> 5, c4 = i & 31;
        int row = rowBase + r;
        float4 va = make_float4(0.f, 0.f, 0.f, 0.f), vh = va;
        if (row < M) {
            va = *(const float4*)&at[(size_t)row * HID + c4 * 4];
            vh = *(const float4*)&hin[(size_t)row * HID + c4 * 4];
        }
        const float* vp = (const float*)&va;
#pragma unroll
        for (int q = 0; q < 4; ++q) {
            unsigned short hi = f2bf(vp[q]);
            Ah[r][c4 * 4 + q] = hi;
            Al[r][c4 * 4 + q] = f2bf(vp[q] - bf2f(hi));
        }
        *(float4*)&Hs[r][c4 * 4] = vh;
    }
    __syncthreads();

    int colW = wave * 32 + l31;

    // GEMM1: Hs += at @ WO + bO
    {
        short8 ah[8], al[8];
#pragma unroll
        for (int kt = 0; kt < 8; ++kt) {
            ah[kt] = *(const short8*)&Ah[l31][kt * 16 + half * 8];
            al[kt] = *(const short8*)&Al[l31][kt * 16 + half * 8];
        }
        size_t fb = (((size_t)(matbase + 3) * 32 + (size_t)wave * 8) * 64 + lane) * 8;
        const unsigned short* Bh = wnh + fb;
        const unsigned short* Bl = wnl + fb;
        short8 bh[8], bl[8];
#pragma unroll
        for (int kt = 0; kt < 8; ++kt) {
            bh[kt] = *(const short8*)&Bh[kt * 512];
            bl[kt] = *(const short8*)&Bl[kt * 512];
        }
        __builtin_amdgcn_sched_barrier(0);
        f32x16 accA = {}, accB = {};
#pragma unroll
        for (int kt = 0; kt < 8; kt += 2) {
            accA = __builtin_amdgcn_mfma_f32_32x32x16_bf16(ah[kt],     bh[kt],     accA, 0, 0, 0);
            accB = __builtin_amdgcn_mfma_f32_32x32x16_bf16(ah[kt + 1], bh[kt + 1], accB, 0, 0, 0);
        }
#pragma unroll
        for (int kt = 0; kt < 8; kt += 2) {
            accA = __builtin_amdgcn_mfma_f32_32x32x16_bf16(al[kt],     bh[kt],     accA, 0, 0, 0);
            accB = __builtin_amdgcn_mfma_f32_32x32x16_bf16(al[kt + 1], bh[kt + 1], accB, 0, 0, 0);
        }
#pragma unroll
        for (int kt = 0; kt < 8; kt += 2) {
            accA = __builtin_amdgcn_mfma_f32_32x32x16_bf16(ah[kt],     bl[kt],     accA, 0, 0, 0);
            accB = __builtin_amdgcn_mfma_f32_32x32x16_bf16(ah[kt + 1], bl[kt + 1], accB, 0, 0, 0);
        }
        float bv = bO[colW];
#pragma unroll
        for (int r = 0; r < 16; ++r) {
            int rowm = (r & 3) + 8 * (r >> 2) + 4 * half;
            Hs[rowm][colW] += accA[r] + accB[r] + bv;
        }
    }
    __syncthreads();

    // LN2: Hs -> Ah/Al
    for (int i = 0; i < 8; ++i) {
        int r = wave * 8 + i;
        float a0 = Hs[r][lane];
        float a1 = Hs[r][64 + lane];
        float s = a0 + a1;
#pragma unroll
        for (int off = 32; off > 0; off >>= 1) s += __shfl_down(s, off, 64);
        s = __shfl(s, 0, 64);
        float mu = s * (1.0f / 128.0f);
        float d0 = a0 - mu, d1 = a1 - mu;
        float v = d0 * d0 + d1 * d1;
#pragma unroll
        for (int off = 32; off > 0; off >>= 1) v += __shfl_down(v, off, 64);
        v = __shfl(v, 0, 64);
        float rr = rsqrtf(v * (1.0f / 128.0f) + 1e-5f);
        float x0 = d0 * rr * g2[lane] + b2g[lane];
        float x1 = d1 * rr * g2[64 + lane] + b2g[64 + lane];
        unsigned short h0 = f2bf(x0), h1 = f2bf(x1);
        Ah[r][lane] = h0;           Ah[r][64 + lane] = h1;
        Al[r][lane] = f2bf(x0 - bf2f(h0));
        Al[r][64 + lane] = f2bf(x1 - bf2f(h1));
    }
    __syncthreads();

    // GEMM2: T = relu(x @ W1 + b1) -> Th/Tl
    {
        short8 ah[8], al[8];
#pragma unroll
        for (int kt = 0; kt < 8; ++kt) {
            ah[kt] = *(const short8*)&Ah[l31][kt * 16 + half * 8];
            al[kt] = *(const short8*)&Al[l31][kt * 16 + half * 8];
        }
        size_t fb = (((size_t)(matbase + 4) * 32 + (size_t)wave * 8) * 64 + lane) * 8;
        const unsigned short* Bh = wnh + fb;
        const unsigned short* Bl = wnl + fb;
        short8 bh[8], bl[8];
#pragma unroll
        for (int kt = 0; kt < 8; ++kt) {
            bh[kt] = *(const short8*)&Bh[kt * 512];
            bl[kt] = *(const short8*)&Bl[kt * 512];
        }
        __builtin_amdgcn_sched_barrier(0);
        f32x16 accA = {}, accB = {};
#pragma unroll
        for (int kt = 0; kt < 8; kt += 2) {
            accA = __builtin_amdgcn_mfma_f32_32x32x16_bf16(ah[kt],     bh[kt],     accA, 0, 0, 0);
            accB = __builtin_amdgcn_mfma_f32_32x32x16_bf16(ah[kt + 1], bh[kt + 1], accB, 0, 0, 0);
        }
#pragma unroll
        for (int kt = 0; kt < 8; kt += 2) {
            accA = __builtin_amdgcn_mfma_f32_32x32x16_bf16(al[kt],     bh[kt],     accA, 0, 0, 0);
            accB = __builtin_amdgcn_mfma_f32_32x32x16_bf16(al[kt + 1], bh[kt + 1], accB, 0, 0, 0);
        }
#pragma unroll
        for (int kt = 0; kt < 8; kt += 2) {
            accA = __builtin_amdgcn_mfma_f32_32x32x16_bf16(ah[kt],     bl[kt],     accA, 0, 0, 0);
            accB = __builtin_amdgcn_mfma_f32_32x32x16_bf16(ah[kt + 1], bl[kt + 1], accB, 0, 0, 0);
        }
        float bv = b1[colW];
#pragma unroll
        for (int r = 0; r < 16; ++r) {
            int rowm = (r & 3) + 8 * (r >> 2) + 4 * half;
            float t = fmaxf(accA[r] + accB[r] + bv, 0.f);
            unsigned short hi = f2bf(t);
            Th[rowm][colW] = hi;
            Tl[rowm][colW] = f2bf(t - bf2f(hi));
        }
    }
    __syncthreads();

    // GEMM3: hout = Hs + T @ W2 + b2
    {
        short8 ah[8], al[8];
#pragma unroll
        for (int kt = 0; kt < 8; ++kt) {
            ah[kt] = *(const short8*)&Th[l31][kt * 16 + half * 8];
            al[kt] = *(const short8*)&Tl[l31][kt * 16 + half * 8];
        }
        size_t fb = (((size_t)(matbase + 5) * 32 + (size_t)wave * 8) * 64 + lane) * 8;
        const unsigned short* Bh = wnh + fb;
        const unsigned short* Bl = wnl + fb;
        short8 bh[8], bl[8];
#pragma unroll
        for (int kt = 0; kt < 8; ++kt) {
            bh[kt] = *(const short8*)&Bh[kt * 512];
            bl[kt] = *(const short8*)&Bl[kt * 512];
        }
        __builtin_amdgcn_sched_barrier(0);
        f32x16 accA = {}, accB = {};
#pragma unroll
        for (int kt = 0; kt < 8; kt += 2) {
            accA = __builtin_amdgcn_mfma_f32_32x32x16_bf16(ah[kt],     bh[kt],     accA, 0, 0, 0);
            accB = __builtin_amdgcn_mfma_f32_32x32x16_bf16(ah[kt + 1], bh[kt + 1], accB, 0, 0, 0);
        }
#pragma unroll
        for (int kt = 0; kt < 8; kt += 2) {
            accA = __builtin_amdgcn_mfma_f32_32x32x16_bf16(al[kt],     bh[kt],     accA, 0, 0, 0);
            accB = __builtin_amdgcn_mfma_f32_32x32x16_bf16(al[kt + 1], bh[kt + 1], accB, 0, 0, 0);
        }
#pragma unroll
        for (int kt = 0; kt < 8; kt += 2) {
            accA = __builtin_amdgcn_mfma_f32_32x32x16_bf16(ah[kt],     bl[kt],     accA, 0, 0, 0);
            accB = __builtin_amdgcn_mfma_f32_32x32x16_bf16(ah[kt + 1], bl[kt + 1], accB, 0, 0, 0);
        }
        float bv = b2[colW];
#pragma unroll
        for (int r = 0; r < 16; ++r) {
            int rowm = (r & 3) + 8 * (r >> 2) + 4 * half;
            int row = rowBase + rowm;
            if (row < M)
                hout[(size_t)row * HID + colW] = Hs[rowm][colW] + accA[r] + accB[r] + bv;
        }
    }
}

// ---------------- CSR build ----------------
__global__ __launch_bounds__(256) void deg_kernel(
    const int* __restrict__ dst, int* __restrict__ deg, int E)
{
    int e = blockIdx.x * 256 + threadIdx.x;
    if (e < E) atomicAdd(&deg[dst[e]], 1);
}

__global__ __launch_bounds__(256) void scan_kernel(
    const int* __restrict__ deg, int* __restrict__ rowptr,
    int* __restrict__ cursor, int N)
{
    __shared__ int sums[256];
    int tid = threadIdx.x;
    int chunk = (N + 255) / 256;
    int lo = tid * chunk;
    int hi = lo + chunk; if (hi > N) hi = N;
    int s = 0;
    for (int i = lo; i < hi && i >= 0; ++i) s += deg[i];
    sums[tid] = s;
    __syncthreads();
    for (int off = 1; off < 256; off <<= 1) {
        int v = (tid >= off) ? sums[tid - off] : 0;
        __syncthreads();
        sums[tid] += v;
        __syncthreads();
    }
    int base = (tid == 0) ? 0 : sums[tid - 1];
    for (int i = lo; i < hi; ++i) {
        rowptr[i] = base; cursor[i] = base; base += deg[i];
    }
    if (tid == 255) rowptr[N] = sums[255];
}

__global__ __launch_bounds__(256) void scatter_kernel(
    const int* __restrict__ src, const int* __restrict__ dst,
    int* __restrict__ cursor, int* __restrict__ ssrc, int E)
{
    int e = blockIdx.x * 256 + threadIdx.x;
    if (e < E) {
        int p = atomicAdd(&cursor[dst[e]], 1);
        ssrc[p] = src[e];
    }
}

// ---------------- fused segment-softmax attention ----------------
__global__ __launch_bounds__(256) void attn_fused_kernel(
    const float* __restrict__ q, const float* __restrict__ k,
    const float* __restrict__ v, const int* __restrict__ rowptr,
    const int* __restrict__ ssrc, float* __restrict__ at, int N)
{
    int node = blockIdx.x * 4 + (threadIdx.x >> 6);
    int lane = threadIdx.x & 63;
    if (node >= N) return;
    int beg = rowptr[node], end = rowptr[node + 1];
    float q0 = q[(size_t)node * HID + lane];
    float q1 = q[(size_t)node * HID + 64 + lane];
    float acc0 = 0.f, acc1 = 0.f, den0 = 0.f, den1 = 0.f;
    for (int i = beg; i < end; ++i) {
        int s = ssrc[i];
        float k0 = k[(size_t)s * HID + lane];
        float k1 = k[(size_t)s * HID + 64 + lane];
        float p0 = q0 * k0, p1 = q1 * k1;
#pragma unroll
        for (int off = 1; off < 16; off <<= 1) {
            p0 += __shfl_xor(p0, off, 64);
            p1 += __shfl_xor(p1, off, 64);
        }
        float w0 = __expf(p0 * 0.25f);
        float w1 = __expf(p1 * 0.25f);
        den0 += w0; den1 += w1;
        acc0 = fmaf(w0, v[(size_t)s * HID + lane], acc0);
        acc1 = fmaf(w1, v[(size_t)s * HID + 64 + lane], acc1);
    }
    at[(size_t)node * HID + lane]      = (den0 > 0.f) ? acc0 / den0 : 0.f;
    at[(size_t)node * HID + 64 + lane] = (den1 > 0.f) ? acc1 / den1 : 0.f;
}

// ---------------- prep: fragment-major packed bf16 MLP hidden weights ----------------
__global__ __launch_bounds__(256) void prep_wp_kernel(
    const float* __restrict__ Wh, unsigned short* __restrict__ wp)
{
    int idx = blockIdx.x * 256 + threadIdx.x;
    if (idx >= 3 * 9 * 18 * 64) return;
    int lane = idx & 63;
    int r = idx >> 6;
    int kt = r % 18; r /= 18;
    int ct = r % 9;
    int layer = r / 9;
    int n = ct * 32 + (lane & 31);
    int kbase = kt * 16 + (lane >> 5) * 8;
    ushort8 val;
#pragma unroll
    for (int j = 0; j < 8; ++j) {
        int k = kbase + j;
        float v = (n < MLP_IN && k < MLP_IN)
            ? Wh[(size_t)layer * MLP_IN * MLP_IN + (size_t)k * MLP_IN + n] : 0.f;
        val[j] = f2bf(v);
    }
    *(ushort8*)&wp[(size_t)idx * 8] = val;
}

__global__ __launch_bounds__(256) void prep_hb_kernel(
    const float* __restrict__ h, unsigned short* __restrict__ hb, int n)
{
    int idx = blockIdx.x * 256 + threadIdx.x;
    if (idx >= n) return;
    hb[idx] = f2bf(h[idx]);
}

// ---------------- fused edge classifier MLP (round-5 version): 32x32x16 MFMA ----------------
__global__ __launch_bounds__(256, 2) void edge_mlp_mfma(
    const unsigned short* __restrict__ hb, const float* __restrict__ ce,
    const float* __restrict__ pe, const float* __restrict__ num,
    const int* __restrict__ src, const int* __restrict__ dst,
    const int* __restrict__ pc, const int* __restrict__ rc,
    const int* __restrict__ pf,
    const unsigned short* __restrict__ wp, const float* __restrict__ bh,
    const float* __restrict__ Wo, const float* __restrict__ bo,
    float* __restrict__ out, int E)
{
    __shared__ unsigned short y[128 * LDW];
    int tid = threadIdx.x;
    int e0 = blockIdx.x * 128;

    for (int i = tid; i < 128 * 36; i += 256) {
        int t = i / 36;
        int c = i - t * 36;
        int e = e0 + t;
        if (e >= E) e = E - 1;
        ushort8 val;
        if (c < 16) {
            val = *(const ushort8*)&hb[(size_t)src[e] * HID + c * 8];
        } else if (c < 32) {
            val = *(const ushort8*)&hb[(size_t)dst[e] * HID + (c - 16) * 8];
        } else if (c == 32) {
            const float* p = &ce[pc[e] * 8];
#pragma unroll
            for (int j = 0; j < 8; ++j) val[j] = f2bf(p[j]);
        } else if (c == 33) {
            const float* p = &ce[rc[e] * 8];
#pragma unroll
            for (int j = 0; j < 8; ++j) val[j] = f2bf(p[j]);
        } else if (c == 34) {
            const float* p = &pe[pf[e] * 8];
#pragma unroll
            for (int j = 0; j < 8; ++j) val[j] = f2bf(p[j]);
        } else {
            const float* p = &num[(size_t)e * 5];
#pragma unroll
            for (int j = 0; j < 5; ++j) val[j] = f2bf(p[j]);
            val[5] = 0; val[6] = 0; val[7] = 0;
        }
        *(ushort8*)&y[t * LDW + c * 8] = val;
    }
    __syncthreads();

    int wave = tid >> 6;
    int lane = tid & 63;
    int l31 = lane & 31;
    int half = lane >> 5;
    int rowA = wave * 32 + l31;

    for (int layer = 0; layer < 3; ++layer) {
        const unsigned short* __restrict__ Wl = wp + (size_t)layer * 9 * 18 * 64 * 8;
        const float* __restrict__ bias = bh + layer * MLP_IN;

        short8 afr[18];
#pragma unroll
        for (int kt = 0; kt < 18; ++kt)
            afr[kt] = *(const short8*)&y[rowA * LDW + kt * 16 + half * 8];
        __syncthreads();

        for (int ct = 0; ct < 9; ++ct) {
            const unsigned short* Wct = Wl + ((size_t)ct * 18 * 64 + lane) * 8;
            short8 bfr[18];
#pragma unroll
            for (int kt = 0; kt < 18; ++kt)
                bfr[kt] = *(const short8*)&Wct[kt * 512];
            __builtin_amdgcn_sched_barrier(0);
            f32x16 accA = {}, accB = {};
#pragma unroll
            for (int kt = 0; kt < 18; kt += 2) {
                accA = __builtin_amdgcn_mfma_f32_32x32x16_bf16(afr[kt],     bfr[kt],     accA, 0, 0, 0);
                accB = __builtin_amdgcn_mfma_f32_32x32x16_bf16(afr[kt + 1], bfr[kt + 1], accB, 0, 0, 0);
            }
            int col = ct * 32 + l31;
            if (col < MLP_IN) {
                float bv = bias[col];
#pragma unroll
                for (int r = 0; r < 16; ++r) {
                    int rowm = (r & 3) + 8 * (r >> 2) + 4 * half;
                    float vv = fmaxf(accA[r] + accB[r] + bv, 0.f);
                    y[(wave * 32 + rowm) * LDW + col] = f2bf(vv);
                }
            }
        }
        __syncthreads();
    }

    {
        int t = tid >> 1, oc = tid & 1;
        int e = e0 + t;
        if (e < E) {
            const unsigned short* yr = &y[t * LDW];
            float p0 = 0.f, p1 = 0.f, p2 = 0.f, p3 = 0.f;
            for (int kc = 0; kc < 35; ++kc) {
                ushort8 yv = *(const ushort8*)&yr[kc * 8];
                int kb = kc * 8;
                p0 = fmaf(bf2f(yv[0]), Wo[(kb + 0) * 2 + oc], p0);
                p1 = fmaf(bf2f(yv[1]), Wo[(kb + 1) * 2 + oc], p1);
                p2 = fmaf(bf2f(yv[2]), Wo[(kb + 2) * 2 + oc], p2);
                p3 = fmaf(bf2f(yv[3]), Wo[(kb + 3) * 2 + oc], p3);
                p0 = fmaf(bf2f(yv[4]), Wo[(kb + 4) * 2 + oc], p0);
                p1 = fmaf(bf2f(yv[5]), Wo[(kb + 5) * 2 + oc], p1);
                p2 = fmaf(bf2f(yv[6]), Wo[(kb + 6) * 2 + oc], p2);
                p3 = fmaf(bf2f(yv[7]), Wo[(kb + 7) * 2 + oc], p3);
            }
            float acc = bo[oc] + (p0 + p1) + (p2 + p3);
            for (int k = 280; k < MLP_IN; ++k)
                acc = fmaf(bf2f(yr[k]), Wo[k * 2 + oc], acc);
            out[(size_t)e * 2 + oc] = acc;
        }
    }
}

extern "C" void kernel_launch(void* const* d_in, const int* in_sizes, int n_in,
                              void* d_out, int out_size, void* d_ws, size_t ws_size,
                              hipStream_t stream)
{
    const float* node_feats = (const float*)d_in[0];
    const float* numericals = (const float*)d_in[1];
    const float* W_emb = (const float*)d_in[2];
    const float* b_emb = (const float*)d_in[3];
    const float* WQ = (const float*)d_in[4];
    const float* bQ = (const float*)d_in[5];
    const float* WK = (const float*)d_in[6];
    const float* bK = (const float*)d_in[7];
    const float* WV = (const float*)d_in[8];
    const float* bV = (const float*)d_in[9];
    const float* WO = (const float*)d_in[10];
    const float* bO = (const float*)d_in[11];
    const float* ln1_g = (const float*)d_in[12];
    const float* ln1_b = (const float*)d_in[13];
    const float* ln2_g = (const float*)d_in[14];
    const float* ln2_b = (const float*)d_in[15];
    const float* W1 = (const float*)d_in[16];
    const float* b1 = (const float*)d_in[17];
    const float* W2 = (const float*)d_in[18];
    const float* b2 = (const float*)d_in[19];
    const float* curr_emb = (const float*)d_in[20];
    const float* pay_emb = (const float*)d_in[21];
    const float* mlp_Wh = (const float*)d_in[22];
    const float* mlp_bh = (const float*)d_in[23];
    const float* mlp_Wo = (const float*)d_in[24];
    const float* mlp_bo = (const float*)d_in[25];
    const int* src = (const int*)d_in[26];
    const int* dst = (const int*)d_in[27];
    const int* pc = (const int*)d_in[28];
    const int* rc = (const int*)d_in[29];
    const int* pf = (const int*)d_in[30];

    const int N = in_sizes[0] / 2;
    const int E = in_sizes[26];

    float* ws = (float*)d_ws;
    float* h   = ws;
    float* x   = h  + (size_t)N * HID;   // unused, layout stability
    float* qb  = x  + (size_t)N * HID;
    float* kb  = qb + (size_t)N * HID;
    float* vb  = kb + (size_t)N * HID;
    float* at  = vb + (size_t)N * HID;
    unsigned short* hb = (unsigned short*)(at + (size_t)N * HID);
    unsigned short* wpk = hb + (size_t)N * HID;
    unsigned short* wnh = wpk + (size_t)3 * 9 * 18 * 64 * 8;
    unsigned short* wnl = wnh + (size_t)42 * 32 * 64 * 8;
    int* rowptr = (int*)(wnl + (size_t)42 * 32 * 64 * 8);
    int* deg    = rowptr + (N + 1);
    int* cursor = deg + N;
    int* ssrc   = cursor + N;

    prep_wp_kernel<<<(3 * 9 * 18 * 64 + 255) / 256, 256, 0, stream>>>(mlp_Wh, wpk);
    prep_nodew_kernel<<<(42 * 32 * 64 + 255) / 256, 256, 0, stream>>>(
        WQ, WK, WV, WO, W1, W2, wnh, wnl);

    embed_kernel<<<(N * HID + 255) / 256, 256, 0, stream>>>(node_feats, W_emb, b_emb, h, N);

    hipMemsetAsync(deg, 0, (size_t)N * sizeof(int), stream);
    deg_kernel<<<(E + 255) / 256, 256, 0, stream>>>(dst, deg, E);
    scan_kernel<<<1, 256, 0, stream>>>(deg, rowptr, cursor, N);
    scatter_kernel<<<(E + 255) / 256, 256, 0, stream>>>(src, dst, cursor, ssrc, E);

    int nodeBlocks = (N + 31) / 32;

    for (int l = 0; l < NLAYERS; ++l) {
        ln_qkv_mfma<<<nodeBlocks, 256, 0, stream>>>(
            h, ln1_g + l * HID, ln1_b + l * HID,
            wnh, wnl, l * 6,
            bQ + l * HID, bK + l * HID, bV + l * HID,
            qb, kb, vb, N);

        attn_fused_kernel<<<(N + 3) / 4, 256, 0, stream>>>(qb, kb, vb, rowptr, ssrc, at, N);

        post_mfma<<<nodeBlocks, 256, 0, stream>>>(
            at, h, wnh, wnl, l * 6,
            bO + l * HID,
            ln2_g + l * HID, ln2_b + l * HID,
            b1 + l * HID, b2 + l * HID,
            h, N);
    }

    prep_hb_kernel<<<(N * HID + 255) / 256, 256, 0, stream>>>(h, hb, N * HID);

    edge_mlp_mfma<<<(E + 127) / 128, 256, 0, stream>>>(
        hb, curr_emb, pay_emb, numericals, src, dst, pc, rc, pf,
        wpk, mlp_bh, mlp_Wo, mlp_bo, (float*)d_out, E);
}

// Round 8
// 1037.642 us; speedup vs baseline: 1.5818x; 1.1265x over previous
//
#include <hip/hip_runtime.h>

#define HID 128
#define NH 8
#define DH 16
#define NLAYERS 7
#define MLP_IN 285
#define MP 288
#define LDW 296         // LDS row stride bf16 elems (edge kernel)
#define XS 136          // LDS row stride for node bf16 tiles

typedef short short8 __attribute__((ext_vector_type(8)));
typedef float f32x4 __attribute__((ext_vector_type(4)));
typedef float f32x16 __attribute__((ext_vector_type(16)));
typedef unsigned short ushort8 __attribute__((ext_vector_type(8)));

__device__ inline unsigned short f2bf(float f) {
    union { float f; unsigned int u; } v; v.f = f;
    unsigned int r = v.u + 0x7FFF + ((v.u >> 16) & 1);
    return (unsigned short)(r >> 16);
}
__device__ inline float bf2f(unsigned short u) {
    union { unsigned int u; float f; } v; v.u = ((unsigned int)u) << 16;
    return v.f;
}

// ---------------- embed ----------------
__global__ __launch_bounds__(256) void embed_kernel(
    const float* __restrict__ nf, const float* __restrict__ We,
    const float* __restrict__ be, float* __restrict__ h, int N)
{
    int idx = blockIdx.x * 256 + threadIdx.x;
    if (idx >= N * HID) return;
    int n = idx >> 7, j = idx & 127;
    h[idx] = fmaf(nf[n * 2], We[j], fmaf(nf[n * 2 + 1], We[HID + j], be[j]));
}

// ---------------- prep: node weights -> fragment-major bf16 hi/lo ----------------
__global__ __launch_bounds__(256) void prep_nodew_kernel(
    const float* __restrict__ WQ, const float* __restrict__ WK,
    const float* __restrict__ WV, const float* __restrict__ WO,
    const float* __restrict__ W1, const float* __restrict__ W2,
    unsigned short* __restrict__ wnh, unsigned short* __restrict__ wnl)
{
    int idx = blockIdx.x * 256 + threadIdx.x;
    if (idx >= 42 * 32 * 64) return;
    int lane = idx & 63;
    int r = idx >> 6;
    int kt = r & 7; r >>= 3;
    int ct = r & 3; r >>= 2;
    int m = r;
    int l = m / 6, wi = m - l * 6;
    const float* Wb;
    switch (wi) {
        case 0: Wb = WQ; break; case 1: Wb = WK; break; case 2: Wb = WV; break;
        case 3: Wb = WO; break; case 4: Wb = W1; break; default: Wb = W2; break;
    }
    Wb += (size_t)l * HID * HID;
    int n = ct * 32 + (lane & 31);
    int kb = kt * 16 + (lane >> 5) * 8;
    ushort8 vh, vl;
#pragma unroll
    for (int j = 0; j < 8; ++j) {
        float w = Wb[(size_t)(kb + j) * HID + n];
        unsigned short hi = f2bf(w);
        vh[j] = hi;
        vl[j] = f2bf(w - bf2f(hi));
    }
    *(ushort8*)&wnh[(size_t)idx * 8] = vh;
    *(ushort8*)&wnl[(size_t)idx * 8] = vl;
}

#define LOADB(m, BH, BL) do { \
    size_t fb_ = (((size_t)(matbase + (m)) * 32 + (size_t)wave * 8) * 64 + lane) * 8; \
    const unsigned short* Bh_ = wnh + fb_; \
    const unsigned short* Bl_ = wnl + fb_; \
    _Pragma("unroll") \
    for (int kt = 0; kt < 8; ++kt) { \
        BH[kt] = *(const short8*)&Bh_[kt * 512]; \
        BL[kt] = *(const short8*)&Bl_[kt * 512]; \
    } \
} while (0)

#define COMPSTORE(BH, BL, BIAS, OUT, STRIDE, OFF) do { \
    f32x16 acc = {}; \
    _Pragma("unroll") \
    for (int kt = 0; kt < 8; ++kt) \
        acc = __builtin_amdgcn_mfma_f32_32x32x16_bf16(ah[kt], BH[kt], acc, 0, 0, 0); \
    _Pragma("unroll") \
    for (int kt = 0; kt < 8; ++kt) \
        acc = __builtin_amdgcn_mfma_f32_32x32x16_bf16(al[kt], BH[kt], acc, 0, 0, 0); \
    _Pragma("unroll") \
    for (int kt = 0; kt < 8; ++kt) \
        acc = __builtin_amdgcn_mfma_f32_32x32x16_bf16(ah[kt], BL[kt], acc, 0, 0, 0); \
    int col_ = wave * 32 + l31; \
    float bv_ = (BIAS)[col_]; \
    _Pragma("unroll") \
    for (int r = 0; r < 16; ++r) { \
        int rowm_ = (r & 3) + 8 * (r >> 2) + 4 * half; \
        int row_ = rowBase + rowm_; \
        if (row_ < M) (OUT)[(size_t)row_ * (STRIDE) + (OFF) + col_] = acc[r] + bv_; \
    } \
} while (0)

// ---------------- fused LN1 + QKV, compensated bf16 MFMA, B ping-pong ----------------
__global__ __launch_bounds__(256, 2) void ln_qkv_mfma(
    const float* __restrict__ h,
    const float* __restrict__ g, const float* __restrict__ bb,
    const unsigned short* __restrict__ wnh, const unsigned short* __restrict__ wnl,
    int matbase,
    const float* __restrict__ bQ, const float* __restrict__ bK, const float* __restrict__ bV,
    float* __restrict__ qo, float* __restrict__ kvo, int M)
{
    __shared__ unsigned short Xh[32][XS];
    __shared__ unsigned short Xl[32][XS];
    int tid = threadIdx.x;
    int lane = tid & 63, wave = tid >> 6;
    int rowBase = blockIdx.x * 32;

    for (int i = 0; i < 8; ++i) {
        int r = wave * 8 + i;
        int row = rowBase + r;
        float a0 = 0.f, a1 = 0.f;
        if (row < M) {
            a0 = h[(size_t)row * HID + lane];
            a1 = h[(size_t)row * HID + 64 + lane];
        }
        float s = a0 + a1;
#pragma unroll
        for (int off = 32; off > 0; off >>= 1) s += __shfl_down(s, off, 64);
        s = __shfl(s, 0, 64);
        float mu = s * (1.0f / 128.0f);
        float d0 = a0 - mu, d1 = a1 - mu;
        float v = d0 * d0 + d1 * d1;
#pragma unroll
        for (int off = 32; off > 0; off >>= 1) v += __shfl_down(v, off, 64);
        v = __shfl(v, 0, 64);
        float rr = rsqrtf(v * (1.0f / 128.0f) + 1e-5f);
        float x0 = d0 * rr * g[lane] + bb[lane];
        float x1 = d1 * rr * g[64 + lane] + bb[64 + lane];
        unsigned short h0 = f2bf(x0), h1 = f2bf(x1);
        Xh[r][lane] = h0;           Xh[r][64 + lane] = h1;
        Xl[r][lane] = f2bf(x0 - bf2f(h0));
        Xl[r][64 + lane] = f2bf(x1 - bf2f(h1));
    }
    __syncthreads();

    int l31 = lane & 31;
    int half = lane >> 5;

    short8 ah[8], al[8];
#pragma unroll
    for (int kt = 0; kt < 8; ++kt) {
        ah[kt] = *(const short8*)&Xh[l31][kt * 16 + half * 8];
        al[kt] = *(const short8*)&Xl[l31][kt * 16 + half * 8];
    }

    short8 bh0[8], bl0[8], bh1[8], bl1[8];
    LOADB(0, bh0, bl0);
    LOADB(1, bh1, bl1);
    COMPSTORE(bh0, bl0, bQ, qo, HID, 0);
    LOADB(2, bh0, bl0);
    COMPSTORE(bh1, bl1, bK, kvo, 256, 0);
    COMPSTORE(bh0, bl0, bV, kvo, 256, 128);
}

// ---------------- fused WO+res -> LN2 -> W1+relu -> W2+res via MFMA ----------------
__global__ __launch_bounds__(256, 2) void post_mfma(
    const float* __restrict__ at, const float* __restrict__ hin,
    const unsigned short* __restrict__ wnh, const unsigned short* __restrict__ wnl,
    int matbase,
    const float* __restrict__ bO,
    const float* __restrict__ g2, const float* __restrict__ b2g,
    const float* __restrict__ b1, const float* __restrict__ b2,
    float* __restrict__ hout, int M)
{
    __shared__ unsigned short Ah[32][XS];
    __shared__ unsigned short Al[32][XS];
    __shared__ unsigned short Th[32][XS];
    __shared__ unsigned short Tl[32][XS];
    __shared__ float Hs[32][132];
    int tid = threadIdx.x;
    int lane = tid & 63, wave = tid >> 6;
    int rowBase = blockIdx.x * 32;
    int l31 = lane & 31;
    int half = lane >> 5;

    for (int i = tid; i < 32 * 32; i += 256) {
        int r = i >> 5, c4 = i & 31;
        int row = rowBase + r;
        float4 va = make_float4(0.f, 0.f, 0.f, 0.f), vh = va;
        if (row < M) {
            va = *(const float4*)&at[(size_t)row * HID + c4 * 4];
            vh = *(const float4*)&hin[(size_t)row * HID + c4 * 4];
        }
        const float* vp = (const float*)&va;
#pragma unroll
        for (int q = 0; q < 4; ++q) {
            unsigned short hi = f2bf(vp[q]);
            Ah[r][c4 * 4 + q] = hi;
            Al[r][c4 * 4 + q] = f2bf(vp[q] - bf2f(hi));
        }
        *(float4*)&Hs[r][c4 * 4] = vh;
    }
    __syncthreads();

    int colW = wave * 32 + l31;

    // GEMM1: Hs += at @ WO + bO
    {
        short8 ah[8], al[8];
#pragma unroll
        for (int kt = 0; kt < 8; ++kt) {
            ah[kt] = *(const short8*)&Ah[l31][kt * 16 + half * 8];
            al[kt] = *(const short8*)&Al[l31][kt * 16 + half * 8];
        }
        short8 bh[8], bl[8];
        {
            size_t fb = (((size_t)(matbase + 3) * 32 + (size_t)wave * 8) * 64 + lane) * 8;
            const unsigned short* Bh = wnh + fb;
            const unsigned short* Bl = wnl + fb;
#pragma unroll
            for (int kt = 0; kt < 8; ++kt) {
                bh[kt] = *(const short8*)&Bh[kt * 512];
                bl[kt] = *(const short8*)&Bl[kt * 512];
            }
        }
        f32x16 acc = {};
#pragma unroll
        for (int kt = 0; kt < 8; ++kt)
            acc = __builtin_amdgcn_mfma_f32_32x32x16_bf16(ah[kt], bh[kt], acc, 0, 0, 0);
#pragma unroll
        for (int kt = 0; kt < 8; ++kt)
            acc = __builtin_amdgcn_mfma_f32_32x32x16_bf16(al[kt], bh[kt], acc, 0, 0, 0);
#pragma unroll
        for (int kt = 0; kt < 8; ++kt)
            acc = __builtin_amdgcn_mfma_f32_32x32x16_bf16(ah[kt], bl[kt], acc, 0, 0, 0);
        float bv = bO[colW];
#pragma unroll
        for (int r = 0; r < 16; ++r) {
            int rowm = (r & 3) + 8 * (r >> 2) + 4 * half;
            Hs[rowm][colW] += acc[r] + bv;
        }
    }
    __syncthreads();

    // LN2
    for (int i = 0; i < 8; ++i) {
        int r = wave * 8 + i;
        float a0 = Hs[r][lane];
        float a1 = Hs[r][64 + lane];
        float s = a0 + a1;
#pragma unroll
        for (int off = 32; off > 0; off >>= 1) s += __shfl_down(s, off, 64);
        s = __shfl(s, 0, 64);
        float mu = s * (1.0f / 128.0f);
        float d0 = a0 - mu, d1 = a1 - mu;
        float v = d0 * d0 + d1 * d1;
#pragma unroll
        for (int off = 32; off > 0; off >>= 1) v += __shfl_down(v, off, 64);
        v = __shfl(v, 0, 64);
        float rr = rsqrtf(v * (1.0f / 128.0f) + 1e-5f);
        float x0 = d0 * rr * g2[lane] + b2g[lane];
        float x1 = d1 * rr * g2[64 + lane] + b2g[64 + lane];
        unsigned short h0 = f2bf(x0), h1 = f2bf(x1);
        Ah[r][lane] = h0;           Ah[r][64 + lane] = h1;
        Al[r][lane] = f2bf(x0 - bf2f(h0));
        Al[r][64 + lane] = f2bf(x1 - bf2f(h1));
    }
    __syncthreads();

    // GEMM2: T = relu(x @ W1 + b1)
    {
        short8 ah[8], al[8];
#pragma unroll
        for (int kt = 0; kt < 8; ++kt) {
            ah[kt] = *(const short8*)&Ah[l31][kt * 16 + half * 8];
            al[kt] = *(const short8*)&Al[l31][kt * 16 + half * 8];
        }
        short8 bh[8], bl[8];
        {
            size_t fb = (((size_t)(matbase + 4) * 32 + (size_t)wave * 8) * 64 + lane) * 8;
            const unsigned short* Bh = wnh + fb;
            const unsigned short* Bl = wnl + fb;
#pragma unroll
            for (int kt = 0; kt < 8; ++kt) {
                bh[kt] = *(const short8*)&Bh[kt * 512];
                bl[kt] = *(const short8*)&Bl[kt * 512];
            }
        }
        f32x16 acc = {};
#pragma unroll
        for (int kt = 0; kt < 8; ++kt)
            acc = __builtin_amdgcn_mfma_f32_32x32x16_bf16(ah[kt], bh[kt], acc, 0, 0, 0);
#pragma unroll
        for (int kt = 0; kt < 8; ++kt)
            acc = __builtin_amdgcn_mfma_f32_32x32x16_bf16(al[kt], bh[kt], acc, 0, 0, 0);
#pragma unroll
        for (int kt = 0; kt < 8; ++kt)
            acc = __builtin_amdgcn_mfma_f32_32x32x16_bf16(ah[kt], bl[kt], acc, 0, 0, 0);
        float bv = b1[colW];
#pragma unroll
        for (int r = 0; r < 16; ++r) {
            int rowm = (r & 3) + 8 * (r >> 2) + 4 * half;
            float t = fmaxf(acc[r] + bv, 0.f);
            unsigned short hi = f2bf(t);
            Th[rowm][colW] = hi;
            Tl[rowm][colW] = f2bf(t - bf2f(hi));
        }
    }
    __syncthreads();

    // GEMM3: hout = Hs + T @ W2 + b2
    {
        short8 ah[8], al[8];
#pragma unroll
        for (int kt = 0; kt < 8; ++kt) {
            ah[kt] = *(const short8*)&Th[l31][kt * 16 + half * 8];
            al[kt] = *(const short8*)&Tl[l31][kt * 16 + half * 8];
        }
        short8 bh[8], bl[8];
        {
            size_t fb = (((size_t)(matbase + 5) * 32 + (size_t)wave * 8) * 64 + lane) * 8;
            const unsigned short* Bh = wnh + fb;
            const unsigned short* Bl = wnl + fb;
#pragma unroll
            for (int kt = 0; kt < 8; ++kt) {
                bh[kt] = *(const short8*)&Bh[kt * 512];
                bl[kt] = *(const short8*)&Bl[kt * 512];
            }
        }
        f32x16 acc = {};
#pragma unroll
        for (int kt = 0; kt < 8; ++kt)
            acc = __builtin_amdgcn_mfma_f32_32x32x16_bf16(ah[kt], bh[kt], acc, 0, 0, 0);
#pragma unroll
        for (int kt = 0; kt < 8; ++kt)
            acc = __builtin_amdgcn_mfma_f32_32x32x16_bf16(al[kt], bh[kt], acc, 0, 0, 0);
#pragma unroll
        for (int kt = 0; kt < 8; ++kt)
            acc = __builtin_amdgcn_mfma_f32_32x32x16_bf16(ah[kt], bl[kt], acc, 0, 0, 0);
        float bv = b2[colW];
#pragma unroll
        for (int r = 0; r < 16; ++r) {
            int rowm = (r & 3) + 8 * (r >> 2) + 4 * half;
            int row = rowBase + rowm;
            if (row < M)
                hout[(size_t)row * HID + colW] = Hs[rowm][colW] + acc[r] + bv;
        }
    }
}

// ---------------- CSR build ----------------
__global__ __launch_bounds__(256) void deg_kernel(
    const int* __restrict__ dst, int* __restrict__ deg, int E)
{
    int e = blockIdx.x * 256 + threadIdx.x;
    if (e < E) atomicAdd(&deg[dst[e]], 1);
}

__global__ __launch_bounds__(256) void scan_kernel(
    const int* __restrict__ deg, int* __restrict__ rowptr,
    int* __restrict__ cursor, int N)
{
    __shared__ int sums[256];
    int tid = threadIdx.x;
    int chunk = (N + 255) / 256;
    int lo = tid * chunk;
    int hi = lo + chunk; if (hi > N) hi = N;
    int s = 0;
    for (int i = lo; i < hi && i >= 0; ++i) s += deg[i];
    sums[tid] = s;
    __syncthreads();
    for (int off = 1; off < 256; off <<= 1) {
        int v = (tid >= off) ? sums[tid - off] : 0;
        __syncthreads();
        sums[tid] += v;
        __syncthreads();
    }
    int base = (tid == 0) ? 0 : sums[tid - 1];
    for (int i = lo; i < hi; ++i) {
        rowptr[i] = base; cursor[i] = base; base += deg[i];
    }
    if (tid == 255) rowptr[N] = sums[255];
}

__global__ __launch_bounds__(256) void scatter_kernel(
    const int* __restrict__ src, const int* __restrict__ dst,
    int* __restrict__ cursor, int* __restrict__ ssrc, int E)
{
    int e = blockIdx.x * 256 + threadIdx.x;
    if (e < E) {
        int p = atomicAdd(&cursor[dst[e]], 1);
        ssrc[p] = src[e];
    }
}

// ---------------- fused segment-softmax attention: 2-edge unroll, kv interleaved ----------------
__global__ __launch_bounds__(256) void attn_fused_kernel(
    const float* __restrict__ q, const float* __restrict__ kv,
    const int* __restrict__ rowptr, const int* __restrict__ ssrc,
    float* __restrict__ at, int N)
{
    int node = blockIdx.x * 4 + (threadIdx.x >> 6);
    int lane = threadIdx.x & 63;
    if (node >= N) return;
    int beg = rowptr[node], end = rowptr[node + 1];
    float q0 = q[(size_t)node * HID + lane];
    float q1 = q[(size_t)node * HID + 64 + lane];
    float acc0 = 0.f, acc1 = 0.f, den0 = 0.f, den1 = 0.f;
    int i = beg;
    for (; i + 2 <= end; i += 2) {
        int s0 = ssrc[i], s1 = ssrc[i + 1];
        const float* kv0 = kv + (size_t)s0 * 256;
        const float* kv1 = kv + (size_t)s1 * 256;
        float k00 = kv0[lane],       k01 = kv0[64 + lane];
        float v00 = kv0[128 + lane], v01 = kv0[192 + lane];
        float k10 = kv1[lane],       k11 = kv1[64 + lane];
        float v10 = kv1[128 + lane], v11 = kv1[192 + lane];
        float p00 = q0 * k00, p01 = q1 * k01;
        float p10 = q0 * k10, p11 = q1 * k11;
#pragma unroll
        for (int off = 1; off < 16; off <<= 1) {
            p00 += __shfl_xor(p00, off, 64);
            p01 += __shfl_xor(p01, off, 64);
            p10 += __shfl_xor(p10, off, 64);
            p11 += __shfl_xor(p11, off, 64);
        }
        float w00 = __expf(p00 * 0.25f), w01 = __expf(p01 * 0.25f);
        float w10 = __expf(p10 * 0.25f), w11 = __expf(p11 * 0.25f);
        den0 += w00 + w10; den1 += w01 + w11;
        acc0 = fmaf(w10, v10, fmaf(w00, v00, acc0));
        acc1 = fmaf(w11, v11, fmaf(w01, v01, acc1));
    }
    if (i < end) {
        int s = ssrc[i];
        const float* kv0 = kv + (size_t)s * 256;
        float k0 = kv0[lane], k1 = kv0[64 + lane];
        float p0 = q0 * k0, p1 = q1 * k1;
#pragma unroll
        for (int off = 1; off < 16; off <<= 1) {
            p0 += __shfl_xor(p0, off, 64);
            p1 += __shfl_xor(p1, off, 64);
        }
        float w0 = __expf(p0 * 0.25f), w1 = __expf(p1 * 0.25f);
        den0 += w0; den1 += w1;
        acc0 = fmaf(w0, kv0[128 + lane], acc0);
        acc1 = fmaf(w1, kv0[192 + lane], acc1);
    }
    at[(size_t)node * HID + lane]      = (den0 > 0.f) ? acc0 / den0 : 0.f;
    at[(size_t)node * HID + 64 + lane] = (den1 > 0.f) ? acc1 / den1 : 0.f;
}

// ---------------- prep: fragment-major packed bf16 MLP hidden weights ----------------
__global__ __launch_bounds__(256) void prep_wp_kernel(
    const float* __restrict__ Wh, unsigned short* __restrict__ wp)
{
    int idx = blockIdx.x * 256 + threadIdx.x;
    if (idx >= 3 * 9 * 18 * 64) return;
    int lane = idx & 63;
    int r = idx >> 6;
    int kt = r % 18; r /= 18;
    int ct = r % 9;
    int layer = r / 9;
    int n = ct * 32 + (lane & 31);
    int kbase = kt * 16 + (lane >> 5) * 8;
    ushort8 val;
#pragma unroll
    for (int j = 0; j < 8; ++j) {
        int k = kbase + j;
        float v = (n < MLP_IN && k < MLP_IN)
            ? Wh[(size_t)layer * MLP_IN * MLP_IN + (size_t)k * MLP_IN + n] : 0.f;
        val[j] = f2bf(v);
    }
    *(ushort8*)&wp[(size_t)idx * 8] = val;
}

__global__ __launch_bounds__(256) void prep_hb_kernel(
    const float* __restrict__ h, unsigned short* __restrict__ hb, int n)
{
    int idx = blockIdx.x * 256 + threadIdx.x;
    if (idx >= n) return;
    hb[idx] = f2bf(h[idx]);
}

#define ELOADB(ct, BUF) do { \
    const unsigned short* Wp_ = Wb + (size_t)(ct) * 9216; \
    _Pragma("unroll") \
    for (int kt = 0; kt < 18; ++kt) BUF[kt] = *(const short8*)&Wp_[kt * 512]; \
} while (0)

#define EMFMA(ct, BUF) do { \
    f32x16 acc = {}; \
    _Pragma("unroll") \
    for (int kt = 0; kt < 18; ++kt) \
        acc = __builtin_amdgcn_mfma_f32_32x32x16_bf16(afr[kt], BUF[kt], acc, 0, 0, 0); \
    int col_ = (ct) * 32 + l31; \
    if (col_ < MLP_IN) { \
        float bv_ = bias[col_]; \
        _Pragma("unroll") \
        for (int r = 0; r < 16; ++r) { \
            int rowm_ = (r & 3) + 8 * (r >> 2) + 4 * half; \
            y[(wave * 32 + rowm_) * LDW + col_] = f2bf(fmaxf(acc[r] + bv_, 0.f)); \
        } \
    } \
} while (0)

// ---------------- fused edge classifier MLP: B register ping-pong ----------------
__global__ __launch_bounds__(256, 2) void edge_mlp_mfma(
    const unsigned short* __restrict__ hb, const float* __restrict__ ce,
    const float* __restrict__ pe, const float* __restrict__ num,
    const int* __restrict__ src, const int* __restrict__ dst,
    const int* __restrict__ pc, const int* __restrict__ rc,
    const int* __restrict__ pf,
    const unsigned short* __restrict__ wp, const float* __restrict__ bh,
    const float* __restrict__ Wo, const float* __restrict__ bo,
    float* __restrict__ out, int E)
{
    __shared__ unsigned short y[128 * LDW];
    int tid = threadIdx.x;
    int e0 = blockIdx.x * 128;

    for (int i = tid; i < 128 * 36; i += 256) {
        int t = i / 36;
        int c = i - t * 36;
        int e = e0 + t;
        if (e >= E) e = E - 1;
        ushort8 val;
        if (c < 16) {
            val = *(const ushort8*)&hb[(size_t)src[e] * HID + c * 8];
        } else if (c < 32) {
            val = *(const ushort8*)&hb[(size_t)dst[e] * HID + (c - 16) * 8];
        } else if (c == 32) {
            const float* p = &ce[pc[e] * 8];
#pragma unroll
            for (int j = 0; j < 8; ++j) val[j] = f2bf(p[j]);
        } else if (c == 33) {
            const float* p = &ce[rc[e] * 8];
#pragma unroll
            for (int j = 0; j < 8; ++j) val[j] = f2bf(p[j]);
        } else if (c == 34) {
            const float* p = &pe[pf[e] * 8];
#pragma unroll
            for (int j = 0; j < 8; ++j) val[j] = f2bf(p[j]);
        } else {
            const float* p = &num[(size_t)e * 5];
#pragma unroll
            for (int j = 0; j < 5; ++j) val[j] = f2bf(p[j]);
            val[5] = 0; val[6] = 0; val[7] = 0;
        }
        *(ushort8*)&y[t * LDW + c * 8] = val;
    }
    __syncthreads();

    int wave = tid >> 6;
    int lane = tid & 63;
    int l31 = lane & 31;
    int half = lane >> 5;
    int rowA = wave * 32 + l31;

    for (int layer = 0; layer < 3; ++layer) {
        const unsigned short* __restrict__ Wl = wp + (size_t)layer * 9 * 18 * 64 * 8;
        const float* __restrict__ bias = bh + layer * MLP_IN;
        const unsigned short* Wb = Wl + (size_t)lane * 8;

        short8 afr[18];
#pragma unroll
        for (int kt = 0; kt < 18; ++kt)
            afr[kt] = *(const short8*)&y[rowA * LDW + kt * 16 + half * 8];
        __syncthreads();

        short8 bA[18], bB[18];
        ELOADB(0, bA);
#pragma unroll
        for (int cp = 0; cp < 4; ++cp) {
            ELOADB(cp * 2 + 1, bB);
            EMFMA(cp * 2, bA);
            ELOADB(cp * 2 + 2, bA);
            EMFMA(cp * 2 + 1, bB);
        }
        EMFMA(8, bA);
        __syncthreads();
    }

    {
        int t = tid >> 1, oc = tid & 1;
        int e = e0 + t;
        if (e < E) {
            const unsigned short* yr = &y[t * LDW];
            float p0 = 0.f, p1 = 0.f, p2 = 0.f, p3 = 0.f;
            for (int kc = 0; kc < 35; ++kc) {
                ushort8 yv = *(const ushort8*)&yr[kc * 8];
                int kb = kc * 8;
                p0 = fmaf(bf2f(yv[0]), Wo[(kb + 0) * 2 + oc], p0);
                p1 = fmaf(bf2f(yv[1]), Wo[(kb + 1) * 2 + oc], p1);
                p2 = fmaf(bf2f(yv[2]), Wo[(kb + 2) * 2 + oc], p2);
                p3 = fmaf(bf2f(yv[3]), Wo[(kb + 3) * 2 + oc], p3);
                p0 = fmaf(bf2f(yv[4]), Wo[(kb + 4) * 2 + oc], p0);
                p1 = fmaf(bf2f(yv[5]), Wo[(kb + 5) * 2 + oc], p1);
                p2 = fmaf(bf2f(yv[6]), Wo[(kb + 6) * 2 + oc], p2);
                p3 = fmaf(bf2f(yv[7]), Wo[(kb + 7) * 2 + oc], p3);
            }
            float acc = bo[oc] + (p0 + p1) + (p2 + p3);
            for (int k = 280; k < MLP_IN; ++k)
                acc = fmaf(bf2f(yr[k]), Wo[k * 2 + oc], acc);
            out[(size_t)e * 2 + oc] = acc;
        }
    }
}

extern "C" void kernel_launch(void* const* d_in, const int* in_sizes, int n_in,
                              void* d_out, int out_size, void* d_ws, size_t ws_size,
                              hipStream_t stream)
{
    const float* node_feats = (const float*)d_in[0];
    const float* numericals = (const float*)d_in[1];
    const float* W_emb = (const float*)d_in[2];
    const float* b_emb = (const float*)d_in[3];
    const float* WQ = (const float*)d_in[4];
    const float* bQ = (const float*)d_in[5];
    const float* WK = (const float*)d_in[6];
    const float* bK = (const float*)d_in[7];
    const float* WV = (const float*)d_in[8];
    const float* bV = (const float*)d_in[9];
    const float* WO = (const float*)d_in[10];
    const float* bO = (const float*)d_in[11];
    const float* ln1_g = (const float*)d_in[12];
    const float* ln1_b = (const float*)d_in[13];
    const float* ln2_g = (const float*)d_in[14];
    const float* ln2_b = (const float*)d_in[15];
    const float* W1 = (const float*)d_in[16];
    const float* b1 = (const float*)d_in[17];
    const float* W2 = (const float*)d_in[18];
    const float* b2 = (const float*)d_in[19];
    const float* curr_emb = (const float*)d_in[20];
    const float* pay_emb = (const float*)d_in[21];
    const float* mlp_Wh = (const float*)d_in[22];
    const float* mlp_bh = (const float*)d_in[23];
    const float* mlp_Wo = (const float*)d_in[24];
    const float* mlp_bo = (const float*)d_in[25];
    const int* src = (const int*)d_in[26];
    const int* dst = (const int*)d_in[27];
    const int* pc = (const int*)d_in[28];
    const int* rc = (const int*)d_in[29];
    const int* pf = (const int*)d_in[30];

    const int N = in_sizes[0] / 2;
    const int E = in_sizes[26];

    float* ws = (float*)d_ws;
    float* h   = ws;
    float* qb  = h   + (size_t)N * HID;
    float* kvb = qb  + (size_t)N * HID;
    float* at  = kvb + (size_t)N * HID * 2;
    unsigned short* hb = (unsigned short*)(at + (size_t)N * HID);
    unsigned short* wpk = hb + (size_t)N * HID;
    unsigned short* wnh = wpk + (size_t)3 * 9 * 18 * 64 * 8;
    unsigned short* wnl = wnh + (size_t)42 * 32 * 64 * 8;
    int* rowptr = (int*)(wnl + (size_t)42 * 32 * 64 * 8);
    int* deg    = rowptr + (N + 1);
    int* cursor = deg + N;
    int* ssrc   = cursor + N;

    prep_wp_kernel<<<(3 * 9 * 18 * 64 + 255) / 256, 256, 0, stream>>>(mlp_Wh, wpk);
    prep_nodew_kernel<<<(42 * 32 * 64 + 255) / 256, 256, 0, stream>>>(
        WQ, WK, WV, WO, W1, W2, wnh, wnl);

    embed_kernel<<<(N * HID + 255) / 256, 256, 0, stream>>>(node_feats, W_emb, b_emb, h, N);

    hipMemsetAsync(deg, 0, (size_t)N * sizeof(int), stream);
    deg_kernel<<<(E + 255) / 256, 256, 0, stream>>>(dst, deg, E);
    scan_kernel<<<1, 256, 0, stream>>>(deg, rowptr, cursor, N);
    scatter_kernel<<<(E + 255) / 256, 256, 0, stream>>>(src, dst, cursor, ssrc, E);

    int nodeBlocks = (N + 31) / 32;

    for (int l = 0; l < NLAYERS; ++l) {
        ln_qkv_mfma<<<nodeBlocks, 256, 0, stream>>>(
            h, ln1_g + l * HID, ln1_b + l * HID,
            wnh, wnl, l * 6,
            bQ + l * HID, bK + l * HID, bV + l * HID,
            qb, kvb, N);

        attn_fused_kernel<<<(N + 3) / 4, 256, 0, stream>>>(qb, kvb, rowptr, ssrc, at, N);

        post_mfma<<<nodeBlocks, 256, 0, stream>>>(
            at, h, wnh, wnl, l * 6,
            bO + l * HID,
            ln2_g + l * HID, ln2_b + l * HID,
            b1 + l * HID, b2 + l * HID,
            h, N);
    }

    prep_hb_kernel<<<(N * HID + 255) / 256, 256, 0, stream>>>(h, hb, N * HID);

    edge_mlp_mfma<<<(E + 127) / 128, 256, 0, stream>>>(
        hb, curr_emb, pay_emb, numericals, src, dst, pc, rc, pf,
        wpk, mlp_bh, mlp_Wo, mlp_bo, (float*)d_out, E);
}